// Round 1
// baseline (65.175 us; speedup 1.0000x reference)
//
#include <hip/hip_runtime.h>

#define IMGW 28
#define OUTW 26
#define FLAT 676
#define NCLS 10
#define FCP  12   // padded LDS stride for transposed fc_w (float4-aligned)

// 256 threads = 4 waves per block; each wave owns one image at a time.
__global__ __launch_bounds__(256, 3) void fused_conv_fc_kernel(
    const float* __restrict__ x,       // [B, 784]
    const float* __restrict__ conv_w,  // [3,3]
    const float* __restrict__ fc_w,    // [10, 676]
    const float* __restrict__ fc_b,    // [10]
    float* __restrict__ out,           // [B, 10]
    int nimg)
{
    __shared__ float lds_fc[FLAT * FCP];          // 32448 B, fcT[f][c]
    __shared__ float lds_img[4][IMGW * IMGW];     // 12544 B, one image per wave

    const int tid  = threadIdx.x;
    const int lane = tid & 63;
    const int widx = tid >> 6;

    // Stage fc_w transposed: lds_fc[f*FCP + c] = fc_w[c*FLAT + f].
    // Global reads coalesced in i; one-time LDS scatter.
    for (int i = tid; i < NCLS * FLAT; i += 256) {
        int c = i / FLAT;
        int f = i - c * FLAT;
        lds_fc[f * FCP + c] = fc_w[i];
    }

    // Broadcast small constants into registers.
    float cw[9];
#pragma unroll
    for (int i = 0; i < 9; ++i) cw[i] = conv_w[i];
    float bias[NCLS];
#pragma unroll
    for (int c = 0; c < NCLS; ++c) bias[c] = fc_b[c];

    __syncthreads();

    const int gw = blockIdx.x * 4 + widx;   // global wave id
    const int nw = gridDim.x * 4;

    for (int img = gw; img < nimg; img += nw) {
        // Load image: 784 f32 = 196 float4, coalesced 1 KiB per wave instr.
        const float4* src = (const float4*)(x + (size_t)img * (IMGW * IMGW));
        float4* dst = (float4*)&lds_img[widx][0];
#pragma unroll
        for (int t = 0; t < 4; ++t) {
            int j = lane + 64 * t;
            if (j < 196) dst[j] = src[j];
        }
        // Same-wave LDS write->read dependency: compiler inserts lgkmcnt waits
        // (same __shared__ array, cannot prove no-alias). No barrier needed.

        float acc[NCLS];
#pragma unroll
        for (int c = 0; c < NCLS; ++c) acc[c] = 0.f;

        const float* im = &lds_img[widx][0];
#pragma unroll
        for (int k = 0; k < 11; ++k) {
            int f = lane + 64 * k;
            if (f < FLAT) {
                int r  = f / OUTW;          // magic-mul div
                int cc = f - r * OUTW;
                const float* p = im + r * IMGW + cc;
                float h = p[0]  * cw[0] + p[1]  * cw[1] + p[2]  * cw[2]
                        + p[28] * cw[3] + p[29] * cw[4] + p[30] * cw[5]
                        + p[56] * cw[6] + p[57] * cw[7] + p[58] * cw[8];
                h = fmaxf(h, 0.f);

                const float4* wf = (const float4*)&lds_fc[f * FCP];
                float4 w0 = wf[0];
                float4 w1 = wf[1];
                float2 w2 = *(const float2*)(&lds_fc[f * FCP + 8]);
                acc[0] += h * w0.x; acc[1] += h * w0.y;
                acc[2] += h * w0.z; acc[3] += h * w0.w;
                acc[4] += h * w1.x; acc[5] += h * w1.y;
                acc[6] += h * w1.z; acc[7] += h * w1.w;
                acc[8] += h * w2.x; acc[9] += h * w2.y;
            }
        }

        // Wave-wide butterfly reduction of the 10 class sums.
#pragma unroll
        for (int c = 0; c < NCLS; ++c) {
            float v = acc[c];
            v += __shfl_xor(v, 1);
            v += __shfl_xor(v, 2);
            v += __shfl_xor(v, 4);
            v += __shfl_xor(v, 8);
            v += __shfl_xor(v, 16);
            v += __shfl_xor(v, 32);
            acc[c] = v;
        }

        if (lane == 0) {
            float* o = out + (size_t)img * NCLS;
#pragma unroll
            for (int c = 0; c < NCLS; ++c) o[c] = acc[c] + bias[c];
        }
    }
}

extern "C" void kernel_launch(void* const* d_in, const int* in_sizes, int n_in,
                              void* d_out, int out_size, void* d_ws, size_t ws_size,
                              hipStream_t stream) {
    const float* x      = (const float*)d_in[0];
    const float* conv_w = (const float*)d_in[1];
    const float* fc_w   = (const float*)d_in[2];
    const float* fc_b   = (const float*)d_in[3];
    float* out = (float*)d_out;

    const int nimg = in_sizes[0] / (IMGW * IMGW);

    const int blocks = 2048;  // 8192 waves -> 4 images per wave at B=32768
    hipLaunchKernelGGL(fused_conv_fc_kernel, dim3(blocks), dim3(256), 0, stream,
                       x, conv_w, fc_w, fc_b, out, nimg);
}

// Round 2
// 61.987 us; speedup vs baseline: 1.0514x; 1.0514x over previous
//
#include <hip/hip_runtime.h>

#define IMGW 28
#define OUTW 26
#define NCLS 10

// lane = image. Each 128-thread block handles 64 images; wave0 computes
// output rows 0..12, wave1 rows 13..25. Conv taps come from a rolling
// 4-row register buffer (all indices compile-time via period-4 unroll).
// conv_w / fc_w / fc_b are read at wave-uniform addresses -> s_load
// (scalar cache), so the VALU does only FMAs and the LDS pipe is idle
// except for a tiny 2.5KB partial handoff.
__global__ __launch_bounds__(128) void fused_conv_fc_kernel(
    const float* __restrict__ x,       // [B, 784]
    const float* __restrict__ conv_w,  // [3,3]
    const float* __restrict__ fc_w,    // [10, 676]
    const float* __restrict__ fc_b,    // [10]
    float* __restrict__ out,           // [B, 10]
    int nimg)
{
    __shared__ float part[64 * NCLS];   // wave1 partial logits

    const int lane = threadIdx.x & 63;
    const int wid  = threadIdx.x >> 6;       // 0 or 1
    const int img  = blockIdx.x * 64 + lane; // grid sized exactly

    const float* ip = x + (size_t)img * (IMGW * IMGW);

    // uniform loads -> SGPRs
    float cw0 = conv_w[0], cw1 = conv_w[1], cw2 = conv_w[2];
    float cw3 = conv_w[3], cw4 = conv_w[4], cw5 = conv_w[5];
    float cw6 = conv_w[6], cw7 = conv_w[7], cw8 = conv_w[8];

    float acc[NCLS];
#pragma unroll
    for (int c = 0; c < NCLS; ++c) acc[c] = 0.f;

    const int s = wid * 13;   // first output row for this wave

    float r0[IMGW], r1[IMGW], r2[IMGW], r3[IMGW];

#define LOADROW(BUF, RR) do {                                        \
    const float4* _p = (const float4*)(ip + (size_t)(RR) * IMGW);    \
    _Pragma("unroll")                                                \
    for (int q = 0; q < 7; ++q) *(float4*)(&BUF[4 * q]) = _p[q];     \
} while (0)

    // conv row from A(row r), B(row r+1), C(row r+2); FC with uniform
    // weights (scalar loads); then prefetch LROW into LBUF (placed after
    // LBUF's last read; ~1 body of cover before first use).
#define BODY(A, B, C, LBUF, LROW, RIDX) do {                          \
    const float* _w = fc_w + (RIDX) * OUTW;                           \
    _Pragma("unroll")                                                 \
    for (int cc = 0; cc < OUTW; ++cc) {                               \
        float h = A[cc]     * cw0 + A[cc + 1] * cw1 + A[cc + 2] * cw2 \
                + B[cc]     * cw3 + B[cc + 1] * cw4 + B[cc + 2] * cw5 \
                + C[cc]     * cw6 + C[cc + 1] * cw7 + C[cc + 2] * cw8;\
        h = fmaxf(h, 0.f);                                            \
        _Pragma("unroll")                                             \
        for (int c = 0; c < NCLS; ++c)                                \
            acc[c] = fmaf(h, _w[c * (OUTW * OUTW) + cc], acc[c]);     \
    }                                                                 \
    { int _lr = (LROW); _lr = _lr > (IMGW - 1) ? (IMGW - 1) : _lr;    \
      LOADROW(LBUF, _lr); }                                           \
} while (0)

    LOADROW(r0, s + 0);
    LOADROW(r1, s + 1);
    LOADROW(r2, s + 2);
    LOADROW(r3, s + 3);

    int r = s;
#pragma unroll 1
    for (int it = 0; it < 3; ++it) {
        BODY(r0, r1, r2, r0, r + 4, r + 0);
        BODY(r1, r2, r3, r1, r + 5, r + 1);
        BODY(r2, r3, r0, r2, r + 6, r + 2);
        BODY(r3, r0, r1, r3, r + 7, r + 3);
        r += 4;
    }
    // body 12 (output row s+12): rows s+12..s+14 in r0,r1,r2; no prefetch
    {
        const float* _w = fc_w + r * OUTW;
#pragma unroll
        for (int cc = 0; cc < OUTW; ++cc) {
            float h = r0[cc]     * cw0 + r0[cc + 1] * cw1 + r0[cc + 2] * cw2
                    + r1[cc]     * cw3 + r1[cc + 1] * cw4 + r1[cc + 2] * cw5
                    + r2[cc]     * cw6 + r2[cc + 1] * cw7 + r2[cc + 2] * cw8;
            h = fmaxf(h, 0.f);
#pragma unroll
            for (int c = 0; c < NCLS; ++c)
                acc[c] = fmaf(h, _w[c * (OUTW * OUTW) + cc], acc[c]);
        }
    }

    // combine the two waves' partials; wave0 writes the output
    if (wid) {
#pragma unroll
        for (int c = 0; c < NCLS; ++c) part[lane * NCLS + c] = acc[c];
    }
    __syncthreads();
    if (!wid) {
        float v[NCLS];
#pragma unroll
        for (int c = 0; c < NCLS; ++c)
            v[c] = acc[c] + part[lane * NCLS + c] + fc_b[c];
        float* o = out + (size_t)img * NCLS;
        // 40B/lane, 8B-aligned -> 5x dwordx2 stores
#pragma unroll
        for (int q = 0; q < 5; ++q)
            *(float2*)(o + 2 * q) = make_float2(v[2 * q], v[2 * q + 1]);
    }
}

extern "C" void kernel_launch(void* const* d_in, const int* in_sizes, int n_in,
                              void* d_out, int out_size, void* d_ws, size_t ws_size,
                              hipStream_t stream) {
    const float* x      = (const float*)d_in[0];
    const float* conv_w = (const float*)d_in[1];
    const float* fc_w   = (const float*)d_in[2];
    const float* fc_b   = (const float*)d_in[3];
    float* out = (float*)d_out;

    const int nimg   = in_sizes[0] / (IMGW * IMGW);  // 32768
    const int blocks = nimg / 64;                    // 512, exact

    hipLaunchKernelGGL(fused_conv_fc_kernel, dim3(blocks), dim3(128), 0, stream,
                       x, conv_w, fc_w, fc_b, out, nimg);
}